// Round 1
// baseline (832.586 us; speedup 1.0000x reference)
//
#include <hip/hip_runtime.h>
#include <hip/hip_bf16.h>
#include <stdint.h>

typedef __attribute__((ext_vector_type(8))) short v8s;
typedef __attribute__((ext_vector_type(4))) short v4s;
typedef __attribute__((ext_vector_type(4))) float v4f;
typedef __attribute__((ext_vector_type(4))) int   v4i;

__device__ __forceinline__ short f2bf(float f) {
  union { float f; uint32_t u; } v; v.f = f;
  uint32_t u = v.u;
  uint32_t r = (u + 0x7fffu + ((u >> 16) & 1u)) >> 16;
  return (short)r;
}

// ---------- prep kernels ----------

// out[o][tap*C + c] = bf16(w[o][c][tap]); w shape [O][C][3][3]
template<int C>
__global__ __launch_bounds__(256) void reorder_w_k(const float* __restrict__ w,
                                                   short* __restrict__ out, int total) {
  int i = blockIdx.x * 256 + threadIdx.x;
  if (i >= total) return;
  int o = i / (C * 9);
  int r = i % (C * 9);
  int tap = r / C;
  int c = r % C;
  out[i] = f2bf(w[(size_t)(o * C + c) * 9 + tap]);
}

// w_off [18][3840][3][3] -> [32][9*3840] (k = tap*3840+c), rows >=18 zero
__global__ __launch_bounds__(256) void prep_woff_k(const float* __restrict__ w,
                                                   short* __restrict__ out) {
  int i = blockIdx.x * 256 + threadIdx.x;
  if (i >= 32 * 34560) return;
  int o = i / 34560;
  int r = i % 34560;
  int tap = r / 3840, c = r % 3840;
  out[i] = (o < 18) ? f2bf(w[(size_t)(o * 3840 + c) * 9 + tap]) : (short)0;
}

// vit [8][3840][14][14] fp32 -> vt [8][196][3840] bf16 (NHWC)
__global__ __launch_bounds__(256) void prep_vt_k(const float* __restrict__ vit,
                                                 short* __restrict__ vt) {
  int i = blockIdx.x * 256 + threadIdx.x;
  if (i >= 8 * 196 * 3840) return;
  int c = i % 3840;
  int bp = i / 3840;
  int p = bp % 196;
  int b = bp / 196;
  vt[i] = f2bf(vit[((size_t)b * 3840 + c) * 196 + p]);
}

// ---------- GEMM ----------
// MODE 0: offset conv (A=woff[32][34560], B=nearest-im2col from vt, dst=partials fp32, split-K)
// MODE 1: deform     (A=wdef[768][6912], B=sp panels, dst=d_t NHWC bf16, +bias)
// MODE 2: conv1 s2   (A=w1r[512][6912], B=im2col(d_t), dst=h_t NHWC bf16, +bias+relu)
// MODE 3: conv2      (A=w2r[768][4608], B=im2col(h_t), dst=out fp32 NCHW, +bias)
template<int MODE, int BM, int BN, int WGM, int CIN, int KTOT, int KSPLIT,
         int NVALID, int IH, int IW, int OW, int STRIDE>
__global__ __launch_bounds__(256) void gemm_k(const short* __restrict__ A,
                                              const void* __restrict__ Bsrc,
                                              const float* __restrict__ bias,
                                              void* __restrict__ dst) {
  constexpr int WGN = 4 / WGM;
  constexpr int WM = BM / WGM;
  constexpr int WN = BN / WGN;
  constexpr int MF = WM / 16;
  constexpr int NF = WN / 16;

  __shared__ __align__(16) short Asm[4][BM][8];
  __shared__ __align__(16) short Bsm[4][BN][8];

  const int tid = threadIdx.x;
  const int lane = tid & 63;
  const int wid = tid >> 6;
  const int wm = wid / WGN, wn = wid % WGN;
  const int n0 = blockIdx.x * BN;
  const int m0 = blockIdx.y * BM;
  const int ts = blockIdx.z;
  const int kbeg = ts * KSPLIT;
  const int kend = kbeg + KSPLIT;
  const int lrow = lane & 15, lkg = lane >> 4;

  v4f acc[MF][NF];
#pragma unroll
  for (int i = 0; i < MF; i++)
#pragma unroll
    for (int j = 0; j < NF; j++) acc[i][j] = (v4f){0.f, 0.f, 0.f, 0.f};

  for (int k = kbeg; k < kend; k += 32) {
    // ---- stage A: BM*4 chunks of 16B, kg-fastest (coalesced global) ----
    for (int ch = tid; ch < BM * 4; ch += 256) {
      int kg = ch & 3, row = ch >> 2;
      v4i v = *(const v4i*)(A + (size_t)(m0 + row) * KTOT + k + kg * 8);
      *(v4i*)(&Asm[kg][row ^ kg][0]) = v;  // xor-swizzle: conflict-free writes
    }
    // ---- stage B: BN*4 chunks, col-fastest ----
    for (int ch = tid; ch < BN * 4; ch += 256) {
      int col = ch % BN, kg = ch / BN;
      int gk = k + kg * 8;
      int n = n0 + col;
      v4i v = (v4i){0, 0, 0, 0};
      if constexpr (MODE == 1) {
        const short* sp = (const short*)Bsrc;
        v = *(const v4i*)(sp + ((size_t)(gk >> 3) * 6272 + n) * 8);
      } else if constexpr (MODE == 0) {
        const short* vt = (const short*)Bsrc;
        int tap = gk / 3840, c0 = gk % 3840;
        int b = n / 784, yx = n % 784;
        int y = yx / 28, x = yx % 28;
        int py = y + tap / 3 - 1, px = x + tap % 3 - 1;
        if (py >= 0 && py < 28 && px >= 0 && px < 28) {
          int pv = (py >> 1) * 14 + (px >> 1);  // fused nearest-resize
          v = *(const v4i*)(vt + ((size_t)(b * 196 + pv) * 3840 + c0));
        }
      } else {
        const short* it = (const short*)Bsrc;
        int tap = gk / CIN, c0 = gk % CIN;
        int b = n / (OW * OW), rem = n % (OW * OW);
        int oy = rem / OW, ox = rem % OW;
        int py = oy * STRIDE + tap / 3 - 1, px = ox * STRIDE + tap % 3 - 1;
        if (n < NVALID && py >= 0 && py < IH && px >= 0 && px < IW) {
          v = *(const v4i*)(it + ((size_t)((b * IH + py) * IW + px) * CIN + c0));
        }
      }
      *(v4i*)(&Bsm[kg][col][0]) = v;
    }
    __syncthreads();
    // ---- fragments + MFMA ----
    v8s af[MF], bfv[NF];
#pragma unroll
    for (int mf = 0; mf < MF; mf++)
      af[mf] = *(const v8s*)(&Asm[lkg][(wm * WM + mf * 16 + lrow) ^ lkg][0]);
#pragma unroll
    for (int nf = 0; nf < NF; nf++)
      bfv[nf] = *(const v8s*)(&Bsm[lkg][wn * WN + nf * 16 + lrow][0]);
#pragma unroll
    for (int mf = 0; mf < MF; mf++)
#pragma unroll
      for (int nf = 0; nf < NF; nf++)
        acc[mf][nf] = __builtin_amdgcn_mfma_f32_16x16x32_bf16(af[mf], bfv[nf], acc[mf][nf], 0, 0, 0);
    __syncthreads();
  }

  // ---- epilogue ----
#pragma unroll
  for (int mf = 0; mf < MF; mf++) {
    int gm = m0 + wm * WM + mf * 16 + lkg * 4;
#pragma unroll
    for (int nf = 0; nf < NF; nf++) {
      int gn = n0 + wn * WN + nf * 16 + lrow;
      v4f a4 = acc[mf][nf];
      if constexpr (MODE == 0) {
        float* part = (float*)dst;
#pragma unroll
        for (int r = 0; r < 4; r++)
          if (gm + r < 18) part[((size_t)ts * 18 + gm + r) * 6272 + gn] = a4[r];
      } else if constexpr (MODE == 1) {
        short* dt = (short*)dst;
        v4s v;
#pragma unroll
        for (int r = 0; r < 4; r++) v[r] = f2bf(a4[r] + bias[gm + r]);
        *(v4s*)(dt + (size_t)gn * 768 + gm) = v;
      } else if constexpr (MODE == 2) {
        if (gn < NVALID) {
          short* ht = (short*)dst;
          v4s v;
#pragma unroll
          for (int r = 0; r < 4; r++) v[r] = f2bf(fmaxf(a4[r] + bias[gm + r], 0.f));
          *(v4s*)(ht + (size_t)gn * 512 + gm) = v;
        }
      } else {
        if (gn < NVALID) {
          float* o = (float*)dst;
          int b = gn / 196, p = gn % 196;
#pragma unroll
          for (int r = 0; r < 4; r++)
            o[((size_t)(b * 768 + gm + r)) * 196 + p] = a4[r] + bias[gm + r];
        }
      }
    }
  }
}

// ---------- offset reduce (+bias) ----------
__global__ __launch_bounds__(256) void reduce_off_k(const float* __restrict__ part,
                                                    const float* __restrict__ boff,
                                                    float* __restrict__ offs) {
  int i = blockIdx.x * 256 + threadIdx.x;
  if (i >= 8 * 18 * 784) return;
  int b = i / (18 * 784), r = i % (18 * 784);
  int o = r / 784, yx = r % 784;
  int n = b * 784 + yx;
  float s = boff[o];
#pragma unroll
  for (int j = 0; j < 8; j++) s += part[((size_t)j * 18 + o) * 6272 + n];
  offs[i] = s;
}

// ---------- bilinear sampling -> sp panels [tap*96 + c/8][n][8] bf16 ----------
__global__ __launch_bounds__(256) void sample_k(const float* __restrict__ cnn,
                                                const float* __restrict__ offs,
                                                short* __restrict__ sp) {
  int n = blockIdx.x * 256 + threadIdx.x;
  if (n >= 6272) return;
  int tap = blockIdx.y;
  int b = n / 784, yx = n % 784;
  int y = yx / 28, x = yx % 28;
  float dy = offs[((size_t)b * 18 + tap * 2 + 0) * 784 + yx];
  float dx = offs[((size_t)b * 18 + tap * 2 + 1) * 784 + yx];
  float py = (float)(y + tap / 3 - 1) + dy;
  float px = (float)(x + tap % 3 - 1) + dx;
  float fy = floorf(py), fx = floorf(px);
  float ly = py - fy, lx = px - fx;
  int y0 = (int)fy, x0 = (int)fx;
  int y1 = y0 + 1, x1 = x0 + 1;
  float vy0 = (y0 >= 0 && y0 < 28) ? 1.f : 0.f;
  float vy1 = (y1 >= 0 && y1 < 28) ? 1.f : 0.f;
  float vx0 = (x0 >= 0 && x0 < 28) ? 1.f : 0.f;
  float vx1 = (x1 >= 0 && x1 < 28) ? 1.f : 0.f;
  float w00 = (1.f - ly) * (1.f - lx) * vy0 * vx0;
  float w01 = (1.f - ly) * lx * vy0 * vx1;
  float w10 = ly * (1.f - lx) * vy1 * vx0;
  float w11 = ly * lx * vy1 * vx1;
  int cy0 = min(max(y0, 0), 27), cy1 = min(max(y1, 0), 27);
  int cx0 = min(max(x0, 0), 27), cx1 = min(max(x1, 0), 27);
  int i00 = cy0 * 28 + cx0, i01 = cy0 * 28 + cx1;
  int i10 = cy1 * 28 + cx0, i11 = cy1 * 28 + cx1;
  const float* base = cnn + (size_t)b * 768 * 784;
  int kgbase = tap * 96;
#pragma unroll 1
  for (int c0 = 0; c0 < 768; c0 += 8) {
    v8s o;
#pragma unroll
    for (int i = 0; i < 8; i++) {
      const float* p = base + (size_t)(c0 + i) * 784;
      float v = w00 * p[i00] + w01 * p[i01] + w10 * p[i10] + w11 * p[i11];
      o[i] = f2bf(v);
    }
    *(v8s*)(sp + ((size_t)(kgbase + (c0 >> 3)) * 6272 + n) * 8) = o;
  }
}

// ---------- launch ----------
extern "C" void kernel_launch(void* const* d_in, const int* in_sizes, int n_in,
                              void* d_out, int out_size, void* d_ws, size_t ws_size,
                              hipStream_t stream) {
  const float* cnn   = (const float*)d_in[0];
  const float* vit   = (const float*)d_in[1];
  const float* w_off = (const float*)d_in[2];
  const float* b_off = (const float*)d_in[3];
  const float* w_def = (const float*)d_in[4];
  const float* b_def = (const float*)d_in[5];
  const float* w1    = (const float*)d_in[6];
  const float* b1    = (const float*)d_in[7];
  const float* w2    = (const float*)d_in[8];
  const float* b2    = (const float*)d_in[9];
  float* out = (float*)d_out;
  char* ws = (char*)d_ws;

  short* wdef_r = (short*)(ws + 0);           // 768*6912*2  = 10,616,832
  short* w1_r   = (short*)(ws + 10616832);    // 512*6912*2  =  7,077,888
  short* w2_r   = (short*)(ws + 17694720);    // 768*4608*2  =  7,077,888
  short* woff_r = (short*)(ws + 24772608);    // 32*34560*2  =  2,211,840
  short* v_t    = (short*)(ws + 26984448);    // 8*196*3840*2 = 12,042,240
  float* part   = (float*)(ws + 39026688);    // 8*18*6272*4 =  3,612,672
  float* offs   = (float*)(ws + 42639360);    // 8*18*784*4  =    451,584
  short* sp     = (short*)(ws + 43090944);    // 6912*6272*2 = 86,704,128
  short* d_t    = (short*)(ws + 129795072);   // 8*784*768*2 =  9,633,792
  short* h_t    = (short*)(ws + 139428864);   // 8*196*512*2 =  1,605,632
  // total 141,034,496 bytes

  dim3 blk(256);
  // prep
  reorder_w_k<768><<<(768 * 6912 + 255) / 256, blk, 0, stream>>>(w_def, wdef_r, 768 * 6912);
  reorder_w_k<768><<<(512 * 6912 + 255) / 256, blk, 0, stream>>>(w1, w1_r, 512 * 6912);
  reorder_w_k<512><<<(768 * 4608 + 255) / 256, blk, 0, stream>>>(w2, w2_r, 768 * 4608);
  prep_woff_k<<<(32 * 34560 + 255) / 256, blk, 0, stream>>>(w_off, woff_r);
  prep_vt_k<<<(8 * 196 * 3840 + 255) / 256, blk, 0, stream>>>(vit, v_t);

  // offset conv: split-K x8 -> partials -> reduce(+bias)
  gemm_k<0, 32, 128, 1, 3840, 34560, 4320, 6272, 28, 28, 28, 1>
      <<<dim3(49, 1, 8), blk, 0, stream>>>(woff_r, v_t, nullptr, part);
  reduce_off_k<<<441, blk, 0, stream>>>(part, b_off, offs);

  // bilinear sampling of cnn_feat per offsets
  sample_k<<<dim3(25, 9, 1), blk, 0, stream>>>(cnn, offs, sp);

  // deformable conv GEMM -> d_t (NHWC bf16)
  gemm_k<1, 128, 128, 2, 768, 6912, 6912, 6272, 28, 28, 28, 1>
      <<<dim3(49, 6, 1), blk, 0, stream>>>(wdef_r, sp, b_def, d_t);

  // conv1 stride 2 + relu -> h_t (NHWC bf16)
  gemm_k<2, 64, 64, 2, 768, 6912, 6912, 1568, 28, 28, 14, 2>
      <<<dim3(25, 8, 1), blk, 0, stream>>>(w1_r, d_t, b1, h_t);

  // conv2 -> out (fp32 NCHW)
  gemm_k<3, 64, 64, 2, 512, 4608, 4608, 1568, 14, 14, 14, 1>
      <<<dim3(25, 12, 1), blk, 0, stream>>>(w2_r, h_t, b2, out);
}

// Round 2
// 588.916 us; speedup vs baseline: 1.4138x; 1.4138x over previous
//
#include <hip/hip_runtime.h>
#include <hip/hip_bf16.h>
#include <stdint.h>

typedef __attribute__((ext_vector_type(8))) short v8s;
typedef __attribute__((ext_vector_type(4))) short v4s;
typedef __attribute__((ext_vector_type(4))) float v4f;

__device__ __forceinline__ short f2bf(float f) {
  union { float f; uint32_t u; } v; v.f = f;
  uint32_t u = v.u;
  uint32_t r = (u + 0x7fffu + ((u >> 16) & 1u)) >> 16;
  return (short)r;
}
__device__ __forceinline__ float bf2f(short s) {
  union { uint32_t u; float f; } v;
  v.u = ((uint32_t)(uint16_t)s) << 16;
  return v.f;
}
__device__ __forceinline__ void gload16(const void* g, void* l) {
  __builtin_amdgcn_global_load_lds(
      (const __attribute__((address_space(1))) void*)g,
      (__attribute__((address_space(3))) void*)l, 16, 0, 0);
}

// ---------- weight panels: out[(k/8)*OP*8 + o*8 + (k&7)] = w[o][c][tap], k=tap*C+c ----------
template<int OP, int OV, int C>
__global__ __launch_bounds__(256) void prep_w_panel(const float* __restrict__ w,
                                                    short* __restrict__ out) {
  int i = blockIdx.x * 256 + threadIdx.x;
  if (i >= OP * C * 9) return;
  int e = i & 7;
  int o = (i >> 3) % OP;
  int p = i / (8 * OP);
  int k = p * 8 + e;
  int tap = k / C, c = k % C;
  out[i] = (o < OV) ? f2bf(w[((size_t)o * C + c) * 9 + tap]) : (short)0;
}

// ---------- [8][C][P] fp32 -> [8*P][C] bf16 (NHWC), LDS-tiled ----------
template<int C, int P>
__global__ __launch_bounds__(256) void transpose_k(const float* __restrict__ in,
                                                   short* __restrict__ out) {
  __shared__ float lds[32][65];
  int n0 = blockIdx.x * 64, c0 = blockIdx.y * 32;
  int t = threadIdx.x;
#pragma unroll
  for (int e = 0; e < 8; e++) {
    int id = e * 256 + t;
    int cl = id >> 6, nl = id & 63;
    int n = n0 + nl;
    if (n < 8 * P) {
      int b = n / P, p = n % P;
      lds[cl][nl] = in[((size_t)b * C + c0 + cl) * P + p];
    }
  }
  __syncthreads();
  int nl = t >> 2, cs = (t & 3) * 8;
  int n = n0 + nl;
  if (n < 8 * P) {
    v8s v;
#pragma unroll
    for (int i = 0; i < 8; i++) v[i] = f2bf(lds[cs + i][nl]);
    *(v8s*)(out + (size_t)n * C + c0 + cs) = v;
  }
}

// ---------- GEMM (all staging via global_load_lds, 16B chunks, linear LDS) ----------
// LDS chunk layout: A chunks [kg][row] at [0, BM*4); B chunks [kg][col] at [BM*4, (BM+BN)*4)
// MODE 0: offset conv   MODE 1: deform   MODE 2: conv1 s2+relu   MODE 3: conv2
template<int MODE, int BM, int BN, int WGM, int AO, int CIN, int KSPLIT,
         int NVALID, int IH, int IW, int OW, int STRIDE>
__global__ __launch_bounds__(256) void gemm_k(const short* __restrict__ Ap,
                                              const short* __restrict__ Bp,
                                              const float* __restrict__ bias,
                                              void* __restrict__ dst,
                                              const short* __restrict__ zp) {
  constexpr int WGN = 4 / WGM;
  constexpr int WM = BM / WGM, WN = BN / WGN;
  constexpr int MF = WM / 16, NF = WN / 16;
  constexpr int CHA = BM * 4, CHT = (BM + BN) * 4;

  __shared__ __align__(16) short SM[CHT * 8];

  const int tid = threadIdx.x;
  const int lane = tid & 63, wid = tid >> 6;
  const int wm = wid / WGN, wn = wid % WGN;
  int bx = blockIdx.x, by = blockIdx.y;
  if constexpr (MODE == 1) {
    // bijective XCD swizzle, nwg = 588 = 8*73 + 4
    int bid = by * 98 + bx;
    int xcd = bid & 7, idx = bid >> 3;
    constexpr int q = 73, r = 4;
    int wg = (xcd < r ? xcd * (q + 1) : r * (q + 1) + (xcd - r) * q) + idx;
    bx = wg % 98; by = wg / 98;
  }
  const int n0 = bx * BN, m0 = by * BM;
  const int ts = blockIdx.z;
  const int kbeg = ts * KSPLIT, kend = kbeg + KSPLIT;
  const int lrow = lane & 15, lkg = lane >> 4;

  v4f acc[MF][NF];
#pragma unroll
  for (int i = 0; i < MF; i++)
#pragma unroll
    for (int j = 0; j < NF; j++) acc[i][j] = (v4f){0.f, 0.f, 0.f, 0.f};

  for (int k = kbeg; k < kend; k += 32) {
    const int kp = k >> 3;
#pragma unroll
    for (int it = 0; it < (CHT + 255) / 256; it++) {
      int ch = it * 256 + tid;
      const short* src = zp;
      if (ch < CHA) {
        int kg = ch / BM, row = ch % BM;
        src = Ap + ((size_t)(kp + kg) * AO + m0 + row) * 8;
      } else if (ch < CHT) {
        int bch = ch - CHA;
        int kg = bch / BN, col = bch % BN;
        int gk = k + kg * 8;
        int n = n0 + col;
        if constexpr (MODE == 1) {
          src = Bp + ((size_t)(kp + kg) * 6272 + n) * 8;
        } else if constexpr (MODE == 0) {
          int tap = gk / 3840, cc = gk % 3840;
          int b = n / 784, yx = n % 784;
          int y = yx / 28 + tap / 3 - 1, x = yx % 28 + tap % 3 - 1;
          src = (y >= 0 && y < 28 && x >= 0 && x < 28)
                  ? Bp + ((size_t)(b * 196 + (y >> 1) * 14 + (x >> 1)) * 3840 + cc)
                  : zp;
        } else {
          int tap = gk / CIN, cc = gk % CIN;
          int b = n / (OW * OW), rem = n % (OW * OW);
          int oy = rem / OW, ox = rem % OW;
          int py = oy * STRIDE + tap / 3 - 1, px = ox * STRIDE + tap % 3 - 1;
          src = (n < NVALID && py >= 0 && py < IH && px >= 0 && px < IW)
                  ? Bp + ((size_t)((b * IH + py) * IW + px) * CIN + cc)
                  : zp;
        }
      }
      if (ch < CHT) gload16(src, &SM[(size_t)(it * 256 + (tid & ~63)) * 8]);
    }
    __syncthreads();

    v8s af[MF], bfv[NF];
#pragma unroll
    for (int mf = 0; mf < MF; mf++)
      af[mf] = *(const v8s*)(SM + ((size_t)(lkg * BM + wm * WM + mf * 16 + lrow)) * 8);
#pragma unroll
    for (int nf = 0; nf < NF; nf++)
      bfv[nf] = *(const v8s*)(SM + ((size_t)(CHA + lkg * BN + wn * WN + nf * 16 + lrow)) * 8);
#pragma unroll
    for (int mf = 0; mf < MF; mf++)
#pragma unroll
      for (int nf = 0; nf < NF; nf++)
        acc[mf][nf] = __builtin_amdgcn_mfma_f32_16x16x32_bf16(af[mf], bfv[nf], acc[mf][nf], 0, 0, 0);
    __syncthreads();
  }

  // ---- epilogue ----
#pragma unroll
  for (int mf = 0; mf < MF; mf++) {
    int gm = m0 + wm * WM + mf * 16 + lkg * 4;
#pragma unroll
    for (int nf = 0; nf < NF; nf++) {
      int gn = n0 + wn * WN + nf * 16 + lrow;
      v4f a4 = acc[mf][nf];
      if constexpr (MODE == 0) {
        float* part = (float*)dst;
#pragma unroll
        for (int r = 0; r < 4; r++)
          if (gm + r < 18) part[((size_t)ts * 18 + gm + r) * 6272 + gn] = a4[r];
      } else if constexpr (MODE == 1) {
        short* dt = (short*)dst;
        v4s v;
#pragma unroll
        for (int r = 0; r < 4; r++) v[r] = f2bf(a4[r] + bias[gm + r]);
        *(v4s*)(dt + (size_t)gn * 768 + gm) = v;
      } else if constexpr (MODE == 2) {
        if (gn < NVALID) {
          short* ht = (short*)dst;
          v4s v;
#pragma unroll
          for (int r = 0; r < 4; r++) v[r] = f2bf(fmaxf(a4[r] + bias[gm + r], 0.f));
          *(v4s*)(ht + (size_t)gn * 512 + gm) = v;
        }
      } else {
        if (gn < NVALID) {
          float* o = (float*)dst;
          int b = gn / 196, p = gn % 196;
#pragma unroll
          for (int r = 0; r < 4; r++)
            o[((size_t)(b * 768 + gm + r)) * 196 + p] = a4[r] + bias[gm + r];
        }
      }
    }
  }
}

// ---------- offset reduce (+bias) ----------
__global__ __launch_bounds__(256) void reduce_off_k(const float* __restrict__ part,
                                                    const float* __restrict__ boff,
                                                    float* __restrict__ offs) {
  int i = blockIdx.x * 256 + threadIdx.x;
  if (i >= 8 * 18 * 784) return;
  int b = i / (18 * 784), r = i % (18 * 784);
  int o = r / 784, yx = r % 784;
  int n = b * 784 + yx;
  float s = boff[o];
#pragma unroll
  for (int j = 0; j < 8; j++) s += part[((size_t)j * 18 + o) * 6272 + n];
  offs[i] = s;
}

// ---------- bilinear sampling from NHWC bf16 -> sp panels [tap*96 + c/8][n][8] ----------
__global__ __launch_bounds__(256) void sample_k(const short* __restrict__ cnn_t,
                                                const float* __restrict__ offs,
                                                short* __restrict__ sp) {
  int n = blockIdx.x * 256 + threadIdx.x;
  if (n >= 6272) return;
  int tap = blockIdx.y;
  int b = n / 784, yx = n % 784;
  int y = yx / 28, x = yx % 28;
  float dy = offs[((size_t)b * 18 + tap * 2 + 0) * 784 + yx];
  float dx = offs[((size_t)b * 18 + tap * 2 + 1) * 784 + yx];
  float py = (float)(y + tap / 3 - 1) + dy;
  float px = (float)(x + tap % 3 - 1) + dx;
  float fy = floorf(py), fx = floorf(px);
  float ly = py - fy, lx = px - fx;
  int y0 = (int)fy, x0 = (int)fx;
  int y1 = y0 + 1, x1 = x0 + 1;
  float vy0 = (y0 >= 0 && y0 < 28) ? 1.f : 0.f;
  float vy1 = (y1 >= 0 && y1 < 28) ? 1.f : 0.f;
  float vx0 = (x0 >= 0 && x0 < 28) ? 1.f : 0.f;
  float vx1 = (x1 >= 0 && x1 < 28) ? 1.f : 0.f;
  float w00 = (1.f - ly) * (1.f - lx) * vy0 * vx0;
  float w01 = (1.f - ly) * lx * vy0 * vx1;
  float w10 = ly * (1.f - lx) * vy1 * vx0;
  float w11 = ly * lx * vy1 * vx1;
  int cy0 = min(max(y0, 0), 27), cy1 = min(max(y1, 0), 27);
  int cx0 = min(max(x0, 0), 27), cx1 = min(max(x1, 0), 27);
  const short* base = cnn_t + (size_t)b * 784 * 768;
  const short* p00 = base + (size_t)(cy0 * 28 + cx0) * 768;
  const short* p01 = base + (size_t)(cy0 * 28 + cx1) * 768;
  const short* p10 = base + (size_t)(cy1 * 28 + cx0) * 768;
  const short* p11 = base + (size_t)(cy1 * 28 + cx1) * 768;
  int kgbase = tap * 96;
  for (int c0 = 0; c0 < 768; c0 += 8) {
    v8s a = *(const v8s*)(p00 + c0);
    v8s bb = *(const v8s*)(p01 + c0);
    v8s c = *(const v8s*)(p10 + c0);
    v8s d = *(const v8s*)(p11 + c0);
    v8s o;
#pragma unroll
    for (int i = 0; i < 8; i++) {
      float v = w00 * bf2f(a[i]) + w01 * bf2f(bb[i]) + w10 * bf2f(c[i]) + w11 * bf2f(d[i]);
      o[i] = f2bf(v);
    }
    *(v8s*)(sp + ((size_t)(kgbase + (c0 >> 3)) * 6272 + n) * 8) = o;
  }
}

// ---------- launch ----------
extern "C" void kernel_launch(void* const* d_in, const int* in_sizes, int n_in,
                              void* d_out, int out_size, void* d_ws, size_t ws_size,
                              hipStream_t stream) {
  const float* cnn   = (const float*)d_in[0];
  const float* vit   = (const float*)d_in[1];
  const float* w_off = (const float*)d_in[2];
  const float* b_off = (const float*)d_in[3];
  const float* w_def = (const float*)d_in[4];
  const float* b_def = (const float*)d_in[5];
  const float* w1    = (const float*)d_in[6];
  const float* b1    = (const float*)d_in[7];
  const float* w2    = (const float*)d_in[8];
  const float* b2    = (const float*)d_in[9];
  float* out = (float*)d_out;
  char* ws = (char*)d_ws;

  short* wdef_p = (short*)(ws + 0);           // 768*6912*2  = 10,616,832
  short* w1_p   = (short*)(ws + 10616832);    // 512*6912*2  =  7,077,888
  short* w2_p   = (short*)(ws + 17694720);    // 768*4608*2  =  7,077,888
  short* woff_p = (short*)(ws + 24772608);    // 32*34560*2  =  2,211,840
  short* v_t    = (short*)(ws + 26984448);    // 8*196*3840*2 = 12,042,240
  float* part   = (float*)(ws + 39026688);    // 8*18*6272*4 =  3,612,672
  float* offs   = (float*)(ws + 42639360);    // 8*18*784*4  =    451,584
  short* sp     = (short*)(ws + 43090944);    // 6912*6272*2 = 86,704,128
  short* d_t    = (short*)(ws + 129795072);   // 8*784*768*2 =  9,633,792
  short* h_t    = (short*)(ws + 139428864);   // 8*196*512*2 =  1,605,632
  short* cnn_t  = (short*)(ws + 141034496);   // 8*784*768*2 =  9,633,792
  short* zp     = (short*)(ws + 150668288);   // 256 zero page
  // total ~150.7 MB

  hipMemsetAsync((void*)zp, 0, 256, stream);

  dim3 blk(256);
  // weight panels
  prep_w_panel<768, 768, 768><<<(768 * 6912 + 255) / 256, blk, 0, stream>>>(w_def, wdef_p);
  prep_w_panel<512, 512, 768><<<(512 * 6912 + 255) / 256, blk, 0, stream>>>(w1, w1_p);
  prep_w_panel<768, 768, 512><<<(768 * 4608 + 255) / 256, blk, 0, stream>>>(w2, w2_p);
  prep_w_panel<32, 18, 3840><<<(32 * 34560 + 255) / 256, blk, 0, stream>>>(w_off, woff_p);
  // NHWC transposes
  transpose_k<3840, 196><<<dim3(25, 120), blk, 0, stream>>>(vit, v_t);
  transpose_k<768, 784><<<dim3(98, 24), blk, 0, stream>>>(cnn, cnn_t);

  // offset conv: split-K x8 -> partials -> reduce(+bias)
  gemm_k<0, 32, 128, 1, 32, 3840, 4320, 6272, 28, 28, 28, 1>
      <<<dim3(49, 1, 8), blk, 0, stream>>>(woff_p, v_t, nullptr, part, zp);
  reduce_off_k<<<441, blk, 0, stream>>>(part, b_off, offs);

  // bilinear sampling
  sample_k<<<dim3(25, 9, 1), blk, 0, stream>>>(cnn_t, offs, sp);

  // deformable conv GEMM -> d_t (NHWC bf16), 128x64 tiles, 588 blocks
  gemm_k<1, 128, 64, 2, 768, 768, 6912, 6272, 28, 28, 28, 1>
      <<<dim3(98, 6, 1), blk, 0, stream>>>(wdef_p, sp, b_def, d_t, zp);

  // conv1 stride 2 + relu -> h_t (NHWC bf16)
  gemm_k<2, 64, 64, 2, 512, 768, 6912, 1568, 28, 28, 14, 2>
      <<<dim3(25, 8, 1), blk, 0, stream>>>(w1_p, d_t, b1, h_t, zp);

  // conv2 -> out (fp32 NCHW)
  gemm_k<3, 64, 64, 2, 768, 512, 4608, 1568, 14, 14, 14, 1>
      <<<dim3(25, 12, 1), blk, 0, stream>>>(w2_p, h_t, b2, out, zp);
}

// Round 3
// 453.286 us; speedup vs baseline: 1.8368x; 1.2992x over previous
//
#include <hip/hip_runtime.h>
#include <hip/hip_bf16.h>
#include <stdint.h>

typedef __attribute__((ext_vector_type(8))) short v8s;
typedef __attribute__((ext_vector_type(4))) short v4s;
typedef __attribute__((ext_vector_type(4))) float v4f;

__device__ __forceinline__ short f2bf(float f) {
  union { float f; uint32_t u; } v; v.f = f;
  uint32_t u = v.u;
  uint32_t r = (u + 0x7fffu + ((u >> 16) & 1u)) >> 16;
  return (short)r;
}
__device__ __forceinline__ float bf2f(short s) {
  union { uint32_t u; float f; } v;
  v.u = ((uint32_t)(uint16_t)s) << 16;
  return v.f;
}
__device__ __forceinline__ void gload16(const void* g, void* l) {
  __builtin_amdgcn_global_load_lds(
      (const __attribute__((address_space(1))) void*)g,
      (__attribute__((address_space(3))) void*)l, 16, 0, 0);
}

// ---------- weight panels: out[(k/8)*OP*8 + o*8 + (k&7)] = w[o][c][tap], k=tap*C+c ----------
template<int OP, int OV, int C>
__global__ __launch_bounds__(256) void prep_w_panel(const float* __restrict__ w,
                                                    short* __restrict__ out) {
  int i = blockIdx.x * 256 + threadIdx.x;
  if (i >= OP * C * 9) return;
  int e = i & 7;
  int o = (i >> 3) % OP;
  int p = i / (8 * OP);
  int k = p * 8 + e;
  int tap = k / C, c = k % C;
  out[i] = (o < OV) ? f2bf(w[((size_t)o * C + c) * 9 + tap]) : (short)0;
}

// ---------- parity-folded offset weights -> panels [pp][kp][32][8], k = tap*3840+c, tap=ty*2+tx ----------
__global__ __launch_bounds__(256) void prep_wfold_k(const float* __restrict__ w,
                                                    short* __restrict__ out) {
  int i = blockIdx.x * 256 + threadIdx.x;
  if (i >= 4 * 1920 * 32 * 8) return;
  int e8 = i & 7;
  int o  = (i >> 3) & 31;
  int kp = (i >> 8) % 1920;
  int pp = i / (1920 * 256);
  int k = kp * 8 + e8;
  int tap = k / 3840, c = k - tap * 3840;
  int ty = tap >> 1, tx = tap & 1;
  int ey = pp >> 1, ex = pp & 1;
  float s = 0.f;
  if (o < 18) {
    const float* wb = w + ((size_t)o * 3840 + c) * 9;
    int dy0 = (ey == 0) ? (ty == 0 ? 0 : 1) : (ty == 0 ? 0 : 2);
    int dy1 = (ey == 0) ? (ty == 0 ? 0 : 2) : (ty == 0 ? 1 : 2);
    int dx0 = (ex == 0) ? (tx == 0 ? 0 : 1) : (tx == 0 ? 0 : 2);
    int dx1 = (ex == 0) ? (tx == 0 ? 0 : 2) : (tx == 0 ? 1 : 2);
    s = wb[dy0 * 3 + dx0];
    if (dx1 != dx0) s += wb[dy0 * 3 + dx1];
    if (dy1 != dy0) {
      s += wb[dy1 * 3 + dx0];
      if (dx1 != dx0) s += wb[dy1 * 3 + dx1];
    }
  }
  out[i] = f2bf(s);
}

// ---------- [8][C][P] fp32 -> [8*P][C] bf16 (NHWC), LDS-tiled ----------
template<int C, int P>
__global__ __launch_bounds__(256) void transpose_k(const float* __restrict__ in,
                                                   short* __restrict__ out) {
  __shared__ float lds[32][65];
  int n0 = blockIdx.x * 64, c0 = blockIdx.y * 32;
  int t = threadIdx.x;
#pragma unroll
  for (int e = 0; e < 8; e++) {
    int id = e * 256 + t;
    int cl = id >> 6, nl = id & 63;
    int n = n0 + nl;
    if (n < 8 * P) {
      int b = n / P, p = n % P;
      lds[cl][nl] = in[((size_t)b * C + c0 + cl) * P + p];
    }
  }
  __syncthreads();
  int nl = t >> 2, cs = (t & 3) * 8;
  int n = n0 + nl;
  if (n < 8 * P) {
    v8s v;
#pragma unroll
    for (int i = 0; i < 8; i++) v[i] = f2bf(lds[cs + i][nl]);
    *(v8s*)(out + (size_t)n * C + c0 + cs) = v;
  }
}

// ---------- GEMM: BK=64, double-buffered prefetch (stage next || compute cur), 1 barrier/iter ----------
// LDS chunks per buf: A [kg(8)][row] then B [kg(8)][col]
// MODE 0: folded offset conv   MODE 1: deform   MODE 2: conv1 s2+relu   MODE 3: conv2
template<int MODE, int BM, int BN, int WGM, int AO, int CIN, int KSPLIT,
         int NVALID, int IH, int IW, int OW, int STRIDE>
__global__ __launch_bounds__(256) void gemm_k(const short* __restrict__ Ap,
                                              const short* __restrict__ Bp,
                                              const float* __restrict__ bias,
                                              void* __restrict__ dst,
                                              const short* __restrict__ zp) {
  constexpr int WGN = 4 / WGM;
  constexpr int WM = BM / WGM, WN = BN / WGN;
  constexpr int MF = WM / 16, NF = WN / 16;
  constexpr int CHA = BM * 8, CHT = (BM + BN) * 8;
  constexpr int NT = KSPLIT / 64;

  __shared__ __align__(16) short SM[2][CHT * 8];

  const int tid = threadIdx.x;
  const int lane = tid & 63, wid = tid >> 6;
  const int wm = wid / WGN, wn = wid % WGN;
  int bx = blockIdx.x, by = blockIdx.y;
  if constexpr (MODE == 1) {
    // bijective XCD swizzle, nwg = 588 = 8*73 + 4
    int bid = by * 98 + bx;
    int xcd = bid & 7, idx = bid >> 3;
    constexpr int q = 73, r = 4;
    int wg = (xcd < r ? xcd * (q + 1) : r * (q + 1) + (xcd - r) * q) + idx;
    bx = wg % 98; by = wg / 98;
  }
  const int n0 = bx * BN, m0 = by * BM;
  const int ts = blockIdx.z;
  int pp = 0, ey = 0, ex = 0;
  if constexpr (MODE == 0) {
    pp = ts >> 2; ey = pp >> 1; ex = pp & 1;
    Ap += (size_t)pp * 1920 * 32 * 8;
  }
  const int kbeg = (MODE == 0 ? (ts & 3) : ts) * KSPLIT;
  const int lrow = lane & 15, lkg = lane >> 4;

  v4f acc[MF][NF];
#pragma unroll
  for (int i = 0; i < MF; i++)
#pragma unroll
    for (int j = 0; j < NF; j++) acc[i][j] = (v4f){0.f, 0.f, 0.f, 0.f};

  auto stage = [&](int k, int buf) {
#pragma unroll
    for (int it = 0; it < CHT / 256; it++) {
      int ch = it * 256 + tid;
      const short* src;
      if (ch < CHA) {
        int kg = ch / BM, row = ch % BM;
        src = Ap + ((size_t)((k >> 3) + kg) * AO + m0 + row) * 8;
      } else {
        int bch = ch - CHA;
        int kg = bch / BN, col = bch % BN;
        int gk = k + kg * 8;
        int n = n0 + col;
        if constexpr (MODE == 1) {
          src = Bp + ((size_t)(gk >> 3) * 6272 + n) * 8;
        } else if constexpr (MODE == 0) {
          int tap = gk / 3840, cc = gk - tap * 3840;
          src = zp;
          if (n < NVALID) {
            int b = n / 196, r2 = n % 196;
            int v = r2 / 14, u = r2 % 14;
            int pv = v + (tap >> 1) - 1 + ey;
            int pu = u + (tap & 1) - 1 + ex;
            if (pv >= 0 && pv < 14 && pu >= 0 && pu < 14)
              src = Bp + ((size_t)(b * 196 + pv * 14 + pu) * 3840 + cc);
          }
        } else {
          int tap = gk / CIN, cc = gk % CIN;
          int b = n / (OW * OW), rem = n % (OW * OW);
          int oy = rem / OW, ox = rem % OW;
          int py = oy * STRIDE + tap / 3 - 1, px = ox * STRIDE + tap % 3 - 1;
          src = (n < NVALID && py >= 0 && py < IH && px >= 0 && px < IW)
                  ? Bp + ((size_t)((b * IH + py) * IW + px) * CIN + cc)
                  : zp;
        }
      }
      gload16(src, &SM[buf][(size_t)(it * 256 + (tid & ~63)) * 8]);
    }
  };

  stage(kbeg, 0);
  __syncthreads();
  int buf = 0;
  for (int t = 0; t < NT; ++t) {
    if (t + 1 < NT) stage(kbeg + (t + 1) * 64, buf ^ 1);
    // compute current buffer
    v8s af[2][MF], bfv[2][NF];
#pragma unroll
    for (int s = 0; s < 2; s++) {
#pragma unroll
      for (int mf = 0; mf < MF; mf++)
        af[s][mf] = *(const v8s*)(&SM[buf][(size_t)((s * 4 + lkg) * BM + wm * WM + mf * 16 + lrow) * 8]);
#pragma unroll
      for (int nf = 0; nf < NF; nf++)
        bfv[s][nf] = *(const v8s*)(&SM[buf][(size_t)(CHA + (s * 4 + lkg) * BN + wn * WN + nf * 16 + lrow) * 8]);
    }
#pragma unroll
    for (int s = 0; s < 2; s++)
#pragma unroll
      for (int mf = 0; mf < MF; mf++)
#pragma unroll
        for (int nf = 0; nf < NF; nf++)
          acc[mf][nf] = __builtin_amdgcn_mfma_f32_16x16x32_bf16(af[s][mf], bfv[s][nf], acc[mf][nf], 0, 0, 0);
    __syncthreads();
    buf ^= 1;
  }

  // ---- epilogue ----
#pragma unroll
  for (int mf = 0; mf < MF; mf++) {
    int gm = m0 + wm * WM + mf * 16 + lkg * 4;
#pragma unroll
    for (int nf = 0; nf < NF; nf++) {
      int gn = n0 + wn * WN + nf * 16 + lrow;
      v4f a4 = acc[mf][nf];
      if constexpr (MODE == 0) {
        float* part = (float*)dst;
        if (gn < NVALID) {
#pragma unroll
          for (int r = 0; r < 4; r++)
            if (gm + r < 18) part[((size_t)ts * 18 + gm + r) * 1568 + gn] = a4[r];
        }
      } else if constexpr (MODE == 1) {
        short* dt = (short*)dst;
        v4s v;
#pragma unroll
        for (int r = 0; r < 4; r++) v[r] = f2bf(a4[r] + bias[gm + r]);
        *(v4s*)(dt + (size_t)gn * 768 + gm) = v;
      } else if constexpr (MODE == 2) {
        if (gn < NVALID) {
          short* ht = (short*)dst;
          v4s v;
#pragma unroll
          for (int r = 0; r < 4; r++) v[r] = f2bf(fmaxf(a4[r] + bias[gm + r], 0.f));
          *(v4s*)(ht + (size_t)gn * 512 + gm) = v;
        }
      } else {
        if (gn < NVALID) {
          float* o = (float*)dst;
          int b = gn / 196, p = gn % 196;
#pragma unroll
          for (int r = 0; r < 4; r++)
            o[((size_t)(b * 768 + gm + r)) * 196 + p] = a4[r] + bias[gm + r];
        }
      }
    }
  }
}

// ---------- offset reduce (+bias): parity partials -> offs[b][18][28][28] ----------
__global__ __launch_bounds__(256) void reduce_off_k(const float* __restrict__ part,
                                                    const float* __restrict__ boff,
                                                    float* __restrict__ offs) {
  int i = blockIdx.x * 256 + threadIdx.x;
  if (i >= 8 * 18 * 784) return;
  int b = i / (18 * 784), r = i % (18 * 784);
  int o = r / 784, yx = r % 784;
  int y = yx / 28, x = yx % 28;
  int pp = (y & 1) * 2 + (x & 1);
  int n = b * 196 + (y >> 1) * 14 + (x >> 1);
  float s = boff[o];
#pragma unroll
  for (int s4 = 0; s4 < 4; s4++)
    s += part[((size_t)(pp * 4 + s4) * 18 + o) * 1568 + n];
  offs[i] = s;
}

// ---------- bilinear sampling, one v8s per thread -> sp panels [tap*96+cch][n][8] ----------
__global__ __launch_bounds__(256) void sample_k(const short* __restrict__ cnn_t,
                                                const float* __restrict__ offs,
                                                short* __restrict__ sp) {
  int n = blockIdx.x * 256 + threadIdx.x;
  if (n >= 6272) return;
  int tap = blockIdx.y / 96, cch = blockIdx.y % 96;
  int b = n / 784, yx = n % 784;
  int y = yx / 28, x = yx % 28;
  float dy = offs[((size_t)b * 18 + tap * 2 + 0) * 784 + yx];
  float dx = offs[((size_t)b * 18 + tap * 2 + 1) * 784 + yx];
  float py = (float)(y + tap / 3 - 1) + dy;
  float px = (float)(x + tap % 3 - 1) + dx;
  float fy = floorf(py), fx = floorf(px);
  float ly = py - fy, lx = px - fx;
  int y0 = (int)fy, x0 = (int)fx;
  int y1 = y0 + 1, x1 = x0 + 1;
  float vy0 = (y0 >= 0 && y0 < 28) ? 1.f : 0.f;
  float vy1 = (y1 >= 0 && y1 < 28) ? 1.f : 0.f;
  float vx0 = (x0 >= 0 && x0 < 28) ? 1.f : 0.f;
  float vx1 = (x1 >= 0 && x1 < 28) ? 1.f : 0.f;
  float w00 = (1.f - ly) * (1.f - lx) * vy0 * vx0;
  float w01 = (1.f - ly) * lx * vy0 * vx1;
  float w10 = ly * (1.f - lx) * vy1 * vx0;
  float w11 = ly * lx * vy1 * vx1;
  int cy0 = min(max(y0, 0), 27), cy1 = min(max(y1, 0), 27);
  int cx0 = min(max(x0, 0), 27), cx1 = min(max(x1, 0), 27);
  const short* base = cnn_t + (size_t)b * 784 * 768;
  int c0 = cch * 8;
  v8s a = *(const v8s*)(base + (size_t)(cy0 * 28 + cx0) * 768 + c0);
  v8s bb = *(const v8s*)(base + (size_t)(cy0 * 28 + cx1) * 768 + c0);
  v8s c = *(const v8s*)(base + (size_t)(cy1 * 28 + cx0) * 768 + c0);
  v8s d = *(const v8s*)(base + (size_t)(cy1 * 28 + cx1) * 768 + c0);
  v8s o;
#pragma unroll
  for (int i = 0; i < 8; i++) {
    float v = w00 * bf2f(a[i]) + w01 * bf2f(bb[i]) + w10 * bf2f(c[i]) + w11 * bf2f(d[i]);
    o[i] = f2bf(v);
  }
  *(v8s*)(sp + ((size_t)(tap * 96 + cch) * 6272 + n) * 8) = o;
}

// ---------- launch ----------
extern "C" void kernel_launch(void* const* d_in, const int* in_sizes, int n_in,
                              void* d_out, int out_size, void* d_ws, size_t ws_size,
                              hipStream_t stream) {
  const float* cnn   = (const float*)d_in[0];
  const float* vit   = (const float*)d_in[1];
  const float* w_off = (const float*)d_in[2];
  const float* b_off = (const float*)d_in[3];
  const float* w_def = (const float*)d_in[4];
  const float* b_def = (const float*)d_in[5];
  const float* w1    = (const float*)d_in[6];
  const float* b1    = (const float*)d_in[7];
  const float* w2    = (const float*)d_in[8];
  const float* b2    = (const float*)d_in[9];
  float* out = (float*)d_out;
  char* ws = (char*)d_ws;

  short* wdef_p = (short*)(ws + 0);           // 10,616,832
  short* w1_p   = (short*)(ws + 10616832);    //  7,077,888
  short* w2_p   = (short*)(ws + 17694720);    //  7,077,888
  short* woff_p = (short*)(ws + 24772608);    //  3,932,160 (folded, 4 parities)
  short* v_t    = (short*)(ws + 28704768);    // 12,042,240
  float* part   = (float*)(ws + 40747008);    //  1,806,336
  float* offs   = (float*)(ws + 42553344);    //    451,584
  short* sp     = (short*)(ws + 43004928);    // 86,704,128
  short* d_t    = (short*)(ws + 129709056);   //  9,633,792
  short* h_t    = (short*)(ws + 139342848);   //  1,605,632
  short* cnn_t  = (short*)(ws + 140948480);   //  9,633,792
  short* zp     = (short*)(ws + 150582272);   // 256 zero page

  hipMemsetAsync((void*)zp, 0, 256, stream);

  dim3 blk(256);
  // weight panels
  prep_w_panel<768, 768, 768><<<(768 * 6912 + 255) / 256, blk, 0, stream>>>(w_def, wdef_p);
  prep_w_panel<512, 512, 768><<<(512 * 6912 + 255) / 256, blk, 0, stream>>>(w1, w1_p);
  prep_w_panel<768, 768, 512><<<(768 * 4608 + 255) / 256, blk, 0, stream>>>(w2, w2_p);
  prep_wfold_k<<<(4 * 1920 * 32 * 8 + 255) / 256, blk, 0, stream>>>(w_off, woff_p);
  // NHWC transposes
  transpose_k<3840, 196><<<dim3(25, 120), blk, 0, stream>>>(vit, v_t);
  transpose_k<768, 784><<<dim3(98, 24), blk, 0, stream>>>(cnn, cnn_t);

  // folded offset conv: z = 4 parities x 4 K-splits -> partials -> reduce(+bias)
  gemm_k<0, 32, 128, 1, 32, 3840, 3840, 1568, 14, 14, 14, 1>
      <<<dim3(13, 1, 16), blk, 0, stream>>>(woff_p, v_t, nullptr, part, zp);
  reduce_off_k<<<441, blk, 0, stream>>>(part, b_off, offs);

  // bilinear sampling (one 16B chunk per thread)
  sample_k<<<dim3(25, 864), blk, 0, stream>>>(cnn_t, offs, sp);

  // deformable conv GEMM -> d_t (NHWC bf16), 128x64 tiles, 588 blocks
  gemm_k<1, 128, 64, 2, 768, 768, 6912, 6272, 28, 28, 28, 1>
      <<<dim3(98, 6, 1), blk, 0, stream>>>(wdef_p, sp, b_def, d_t, zp);

  // conv1 stride 2 + relu -> h_t (NHWC bf16)
  gemm_k<2, 64, 64, 2, 512, 768, 6912, 1568, 28, 28, 14, 2>
      <<<dim3(25, 8, 1), blk, 0, stream>>>(w1_p, d_t, b1, h_t, zp);

  // conv2 -> out (fp32 NCHW)
  gemm_k<3, 64, 64, 2, 768, 512, 4608, 1568, 14, 14, 14, 1>
      <<<dim3(25, 12, 1), blk, 0, stream>>>(w2_p, h_t, b2, out, zp);
}